// Round 11
// baseline (401.928 us; speedup 1.0000x reference)
//
#include <hip/hip_runtime.h>
#include <hip/hip_bf16.h>

#define N_NODES 20000
#define NEDGE   320000
#define DIM     128
#define NH      4
#define HD      512   // NH*DIM
#define LAYERS  3
#define EPS_RMS 1.1920929e-07f
#define SLOPE   0.2f
#define NTILES  (N_NODES >> 4)   // 1250

typedef __bf16 bf16_t;
typedef __bf16 bf16v2 __attribute__((ext_vector_type(2)));
typedef __bf16 bf16v8 __attribute__((ext_vector_type(8)));
typedef float  f32v4  __attribute__((ext_vector_type(4)));
typedef float  f32v2  __attribute__((ext_vector_type(2)));

__device__ __forceinline__ int clamp_node(int s) {
    return ((unsigned)s >= (unsigned)N_NODES) ? 0 : s;
}
__device__ __forceinline__ float leaky(float e) { return e > 0.f ? e : SLOPE * e; }
__device__ __forceinline__ unsigned char enc_fp8(float v) {
    int p = __builtin_amdgcn_cvt_pk_fp8_f32(v, v, 0, false);
    return (unsigned char)(p & 0xff);
}
__device__ __forceinline__ unsigned short enc_fp8_pair(float a, float b) {
    int p = __builtin_amdgcn_cvt_pk_fp8_f32(a, b, 0, false);
    return (unsigned short)(p & 0xffff);
}

// ---- per-wave dtype detection ----
__device__ __forceinline__ bool wave_detect_bf16(const unsigned short* xh) {
    int lane = threadIdx.x & 63;
    unsigned short hw = xh[2 * lane];
    int e = (hw >> 7) & 0xff;
    unsigned long long b = __ballot(e >= 96 && e <= 140);
    return __popcll(b) >= 48;
}
__device__ __forceinline__ bool wave_detect_i64(const int* ei) {
    int lane = threadIdx.x & 63;
    unsigned long long b = __ballot(ei[2 * lane + 1] != 0);
    return b == 0ULL;
}
__device__ __forceinline__ float raw_elem(const void* in, size_t j, bool isbf) {
    return isbf ? (float)((const bf16_t*)in)[j] : ((const float*)in)[j];
}
__device__ __forceinline__ bf16_t cvt_elem(const void* in, size_t j, bool isbf) {
    return isbf ? ((const bf16_t*)in)[j] : (bf16_t)((const float*)in)[j];
}
__device__ __forceinline__ int edge_src(const int* ei, int e, bool is64) {
    return clamp_node(is64 ? ei[2 * e] : ei[e]);
}
__device__ __forceinline__ int edge_dst(const int* ei, int e, bool is64) {
    return clamp_node(is64 ? ei[2 * NEDGE + 2 * e] : ei[NEDGE + e]);
}

// ---------------- prep_v: v_s/v_d[l][h][k] = sum_c Wg[l][k][h*128+c] * att[l][h][c] ----------------
__global__ __launch_bounds__(256) void prep_v(const void* x, const void* Wg,
                                              const void* aS, const void* aD,
                                              float* __restrict__ vS, float* __restrict__ vD) {
    bool isbf = wave_detect_bf16((const unsigned short*)x);
    int w = (int)((blockIdx.x * blockDim.x + threadIdx.x) >> 6);
    if (w >= LAYERS * DIM * NH * 2) return;
    int lane = threadIdx.x & 63;
    int sd = w & 1, h = (w >> 1) & 3, k = (w >> 3) & 127, l = w >> 10;
    const void* att = sd ? aD : aS;
    size_t wbase = (size_t)l * DIM * HD + (size_t)k * HD + h * DIM;
    size_t abase = (size_t)l * NH * DIM + (size_t)h * DIM;
    int c = 2 * lane;
    float p = raw_elem(Wg, wbase + c, isbf) * raw_elem(att, abase + c, isbf)
            + raw_elem(Wg, wbase + c + 1, isbf) * raw_elem(att, abase + c + 1, isbf);
#pragma unroll
    for (int msk = 1; msk < 64; msk <<= 1) p += __shfl_xor(p, msk);
    if (lane == 0) {
        float* dst = sd ? vD : vS;
        dst[l * HD + h * DIM + k] = p;
    }
}

// ---------------- mega: convert + hist + asd_x8 (layer-0 coefs from raw x) ----------------
__global__ __launch_bounds__(256) void mega_setup(
        const void* x, const void* Wg, const void* W1, const void* W2,
        const void* bg, const void* b1, const void* b2, const void* n1, const void* n2,
        bf16_t* xb, bf16_t* WmixT, bf16_t* W1T, bf16_t* W2T,
        bf16_t* bgc, bf16_t* b1c, bf16_t* b2c, bf16_t* n1c, bf16_t* n2c,
        const int* ei, int* deg,
        const float* vS, const float* vD,
        float* a_s, float* a_d, unsigned short* x8,
        int convBlocks, int histBlocks) {
    const int NX  = N_NODES * DIM;
    const int NWG = LAYERS * DIM * HD;
    const int NW1 = LAYERS * DIM * DIM;
    const int NV  = LAYERS * DIM;
    int b = (int)blockIdx.x;
    if (b >= convBlocks + histBlocks) {   // asd_x8 part: wave per node
        bool isbf = wave_detect_bf16((const unsigned short*)x);
        int lane = threadIdx.x & 63;
        int n = (b - convBlocks - histBlocks) * 4 + (int)(threadIdx.x >> 6);
        if (n >= N_NODES) return;
        int c = 2 * lane;
        float f0 = raw_elem(x, (size_t)n * DIM + c, isbf);
        float f1 = raw_elem(x, (size_t)n * DIM + c + 1, isbf);
        x8[n * 64 + lane] = enc_fp8_pair(f0, f1);
#pragma unroll
        for (int h = 0; h < NH; ++h) {
            float ps = f0 * vS[h * DIM + c] + f1 * vS[h * DIM + c + 1];
            float pd = f0 * vD[h * DIM + c] + f1 * vD[h * DIM + c + 1];
#pragma unroll
            for (int msk = 1; msk < 64; msk <<= 1) {
                ps += __shfl_xor(ps, msk);
                pd += __shfl_xor(pd, msk);
            }
            if (lane == 0) {
                a_s[n * 4 + h] = ps;
                a_d[n * 4 + h] = pd;
            }
        }
        return;
    }
    if (b >= convBlocks) {   // histogram
        bool is64 = wave_detect_i64(ei);
        int e = (b - convBlocks) * 256 + threadIdx.x;
        if (e < NEDGE) atomicAdd(&deg[edge_dst(ei, e, is64)], 1);
        return;
    }
    bool isbf = wave_detect_bf16((const unsigned short*)x);
    int i = b * 256 + threadIdx.x;
    if (i < NX) { xb[i] = cvt_elem(x, i, isbf); return; }
    i -= NX;
    if (i < NWG) {   // WmixT[l][c][h*128+k] = Wg[l][k][h*128+c]
        int l = i / (DIM * HD);
        int rem = i - l * (DIM * HD);
        int c = rem / HD, kp = rem - c * HD;
        int h = kp >> 7, k = kp & 127;
        WmixT[i] = cvt_elem(Wg, (size_t)l * DIM * HD + (size_t)k * HD + h * DIM + c, isbf);
        return;
    }
    i -= NWG;
    if (i < NW1) {
        int l = i / (DIM * DIM);
        int rem = i - l * (DIM * DIM);
        int c = rem / DIM, k = rem - c * DIM;
        W1T[i] = cvt_elem(W1, (size_t)l * DIM * DIM + (size_t)k * DIM + c, isbf);
        return;
    }
    i -= NW1;
    if (i < NW1) {
        int l = i / (DIM * DIM);
        int rem = i - l * (DIM * DIM);
        int c = rem / DIM, k = rem - c * DIM;
        W2T[i] = cvt_elem(W2, (size_t)l * DIM * DIM + (size_t)k * DIM + c, isbf);
        return;
    }
    i -= NW1;
    if (i >= 5 * NV) return;
    int seg = i / NV, k = i - seg * NV;
    if (seg == 0) bgc[k] = cvt_elem(bg, k, isbf);
    else if (seg == 1) b1c[k] = cvt_elem(b1, k, isbf);
    else if (seg == 2) b2c[k] = cvt_elem(b2, k, isbf);
    else if (seg == 3) n1c[k] = cvt_elem(n1, k, isbf);
    else n2c[k] = cvt_elem(n2, k, isbf);
}

__global__ __launch_bounds__(1024) void scan_kernel(const int* __restrict__ deg,
                                                    int* __restrict__ row_ptr,
                                                    int* __restrict__ cursor) {
    __shared__ int wsum[16];
    __shared__ int carry_s;
    int tid = threadIdx.x, lane = tid & 63, wv = tid >> 6;
    if (tid == 0) { carry_s = 0; row_ptr[0] = 0; }
    __syncthreads();
    for (int base = 0; base < N_NODES; base += 1024) {
        int idx = base + tid;
        int v = (idx < N_NODES) ? deg[idx] : 0;
        int x = v;
#pragma unroll
        for (int off = 1; off < 64; off <<= 1) {
            int t = __shfl_up(x, off);
            if (lane >= off) x += t;
        }
        if (lane == 63) wsum[wv] = x;
        __syncthreads();
        if (wv == 0) {
            int s = (lane < 16) ? wsum[lane] : 0;
#pragma unroll
            for (int off = 1; off < 16; off <<= 1) {
                int t = __shfl_up(s, off);
                if (lane >= off) s += t;
            }
            if (lane < 16) wsum[lane] = s;
        }
        __syncthreads();
        int woff = (wv == 0) ? 0 : wsum[wv - 1];
        int c = carry_s;
        int incl = x + woff + c;
        if (idx < N_NODES) {
            row_ptr[idx + 1] = incl;
            cursor[idx] = incl - v;
        }
        __syncthreads();
        if (tid == 1023) carry_s = incl;
        __syncthreads();
    }
}

__global__ void fill_kernel(const int* __restrict__ ei, int* __restrict__ cursor,
                            int* __restrict__ csr_src) {
    bool is64 = wave_detect_i64(ei);
    int e = blockIdx.x * blockDim.x + threadIdx.x;
    if (e < NEDGE) {
        int d = edge_dst(ei, e, is64);
        int pos = atomicAdd(&cursor[d], 1);
        if ((unsigned)pos < (unsigned)NEDGE) csr_src[pos] = edge_src(ei, e, is64);
    }
}

// ---------------- gat_gather (single-pass softmax, no LDS, one wave/node) ----------------
// |e| = |a_s + a_d| << 1 analytically -> exp without max-stabilization is safe
// and yields the mathematically identical softmax (div by Z at the end).
__global__ __launch_bounds__(256) void gat_gather(const int* __restrict__ row_ptr,
                                                  const int* __restrict__ csr_src,
                                                  const float* __restrict__ a_s,
                                                  const float* __restrict__ a_d,
                                                  const unsigned short* __restrict__ x8,
                                                  bf16_t* __restrict__ y) {
    int n = (int)((blockIdx.x * blockDim.x + threadIdx.x) >> 6);
    if (n >= N_NODES) return;
    int lane = threadIdx.x & 63;
    int beg = row_ptr[n];
    int deg = row_ptr[n + 1] - beg;
    if (deg < 0) deg = 0;
    if (deg > NEDGE) deg = NEDGE;
    if (beg < 0) beg = 0;
    if (beg > NEDGE - deg) beg = NEDGE - deg;

    const float4* a_s4 = reinterpret_cast<const float4*>(a_s);
    const float4 adv = reinterpret_cast<const float4*>(a_d)[n];
    const float4 avs = a_s4[n];
    unsigned short pself = x8[n * 64 + lane];
    int s_reg = (lane < deg) ? clamp_node(csr_src[beg + lane]) : n;

    float4 ws = {__expf(leaky(avs.x + adv.x)), __expf(leaky(avs.y + adv.y)),
                 __expf(leaky(avs.z + adv.z)), __expf(leaky(avs.w + adv.w))};
    float4 z4 = ws;
    float acc[8];
    {
        f32v2 f = __builtin_amdgcn_cvt_pk_f32_fp8((int)pself, false);
        acc[0] = ws.x * f[0]; acc[1] = ws.x * f[1];
        acc[2] = ws.y * f[0]; acc[3] = ws.y * f[1];
        acc[4] = ws.z * f[0]; acc[5] = ws.z * f[1];
        acc[6] = ws.w * f[0]; acc[7] = ws.w * f[1];
    }

    for (int b0 = 0; b0 < deg; b0 += 8) {
        int cnt = deg - b0; if (cnt > 8) cnt = 8;
        unsigned short xe[8]; float4 av[8];
#pragma unroll
        for (int u = 0; u < 8; ++u) {
            if (u < cnt) {
                int e = b0 + u;
                int s = (e < 64) ? __shfl(s_reg, e) : clamp_node(csr_src[beg + e]);
                av[u] = a_s4[s];          // wave-uniform address -> 1 line
                xe[u] = x8[s * 64 + lane]; // 1 contiguous 128-B line
            }
        }
#pragma unroll
        for (int u = 0; u < 8; ++u) {
            if (u < cnt) {
                float4 w = {__expf(leaky(av[u].x + adv.x)), __expf(leaky(av[u].y + adv.y)),
                            __expf(leaky(av[u].z + adv.z)), __expf(leaky(av[u].w + adv.w))};
                z4.x += w.x; z4.y += w.y; z4.z += w.z; z4.w += w.w;
                f32v2 f = __builtin_amdgcn_cvt_pk_f32_fp8((int)xe[u], false);
                acc[0] += w.x * f[0]; acc[1] += w.x * f[1];
                acc[2] += w.y * f[0]; acc[3] += w.y * f[1];
                acc[4] += w.z * f[0]; acc[5] += w.z * f[1];
                acc[6] += w.w * f[0]; acc[7] += w.w * f[1];
            }
        }
    }
    float4 ih4 = {1.f / z4.x, 1.f / z4.y, 1.f / z4.z, 1.f / z4.w};
    int c = 2 * lane;
#pragma unroll
    for (int h = 0; h < NH; ++h) {
        float ih = h == 0 ? ih4.x : h == 1 ? ih4.y : h == 2 ? ih4.z : ih4.w;
        bf16v2 o;
        o[0] = (bf16_t)(acc[h * 2 + 0] * ih);
        o[1] = (bf16_t)(acc[h * 2 + 1] * ih);
        *reinterpret_cast<bf16v2*>(&y[(size_t)n * HD + h * DIM + c]) = o;
    }
}

// ---------------- mix_ffn: one block = 16 nodes; mix (N-split, K=512) + FFN ----------------
// MODE 0: writes bf16 xb + next-layer x8/a_s/a_d.  MODE 1: writes f32 d_out.
template <int MODE>
__global__ __launch_bounds__(256) void mix_ffn(
        const bf16_t* __restrict__ y,
        const bf16_t* __restrict__ WmixT, const bf16_t* __restrict__ bg,
        const bf16_t* __restrict__ n1w, const bf16_t* __restrict__ xb,
        const bf16_t* __restrict__ W1T, const bf16_t* __restrict__ b1,
        const bf16_t* __restrict__ W2T, const bf16_t* __restrict__ b2,
        const bf16_t* __restrict__ n2w, void* __restrict__ out,
        const float* __restrict__ vS, const float* __restrict__ vD,
        float* __restrict__ a_s_n, float* __restrict__ a_d_n,
        unsigned char* __restrict__ x8_n) {
    __shared__ bf16_t xm[16][136];
    __shared__ bf16_t hh[16][136];
    __shared__ float  ssq_p[16][4];
    __shared__ float  asd_p[4][16][8];
    int tile = blockIdx.x;
    int wv = threadIdx.x >> 6;
    int lane = threadIdx.x & 63;
    int m = lane & 15, kq = lane >> 4;

    // ---- mix: wave wv computes cols [32wv, 32wv+32), K=512 from global y ----
    f32v4 accm[2];
    accm[0] = (f32v4){0.f, 0.f, 0.f, 0.f};
    accm[1] = (f32v4){0.f, 0.f, 0.f, 0.f};
    {
        const bf16_t* Ar = y + (size_t)(tile * 16 + m) * HD + kq * 8;
        const bf16_t* Bc = WmixT + (size_t)(32 * wv + m) * HD + kq * 8;
#pragma unroll
        for (int kk = 0; kk < 16; ++kk) {
            bf16v8 a = *reinterpret_cast<const bf16v8*>(Ar + kk * 32);
#pragma unroll
            for (int tt = 0; tt < 2; ++tt) {
                bf16v8 b = *reinterpret_cast<const bf16v8*>(Bc + (size_t)tt * 16 * HD + kk * 32);
                accm[tt] = __builtin_amdgcn_mfma_f32_16x16x32_bf16(a, b, accm[tt], 0, 0, 0);
            }
        }
    }
    float vals[2][4];
    {
        float sp[4] = {0.f, 0.f, 0.f, 0.f};
#pragma unroll
        for (int tt = 0; tt < 2; ++tt) {
            int col = 32 * wv + tt * 16 + m;
            float bv = (float)bg[col];
#pragma unroll
            for (int r = 0; r < 4; ++r) {
                int gr = tile * 16 + kq * 4 + r;
                float v = 0.25f * accm[tt][r] + bv + (float)xb[(size_t)gr * DIM + col];
                vals[tt][r] = v;
                sp[r] += v * v;
            }
        }
#pragma unroll
        for (int r = 0; r < 4; ++r) {
            sp[r] += __shfl_xor(sp[r], 1); sp[r] += __shfl_xor(sp[r], 2);
            sp[r] += __shfl_xor(sp[r], 4); sp[r] += __shfl_xor(sp[r], 8);
            if (m == r) ssq_p[kq * 4 + r][wv] = sp[r];
        }
    }
    __syncthreads();
    {
#pragma unroll
        for (int r = 0; r < 4; ++r) {
            int row = kq * 4 + r;
            float s = ssq_p[row][0] + ssq_p[row][1] + ssq_p[row][2] + ssq_p[row][3];
            float scale = rsqrtf(s * (1.f / 128.f) + EPS_RMS);
#pragma unroll
            for (int tt = 0; tt < 2; ++tt) {
                int col = 32 * wv + tt * 16 + m;
                xm[row][col] = (bf16_t)(vals[tt][r] * scale * (float)n1w[col]);
            }
        }
    }
    __syncthreads();

    // ---- FFN (N-split) ----
    f32v4 acc1[2];
    acc1[0] = (f32v4){0.f, 0.f, 0.f, 0.f};
    acc1[1] = (f32v4){0.f, 0.f, 0.f, 0.f};
#pragma unroll
    for (int ks = 0; ks < 4; ++ks) {
        bf16v8 a = *reinterpret_cast<const bf16v8*>(&xm[m][ks * 32 + kq * 8]);
#pragma unroll
        for (int tt = 0; tt < 2; ++tt) {
            bf16v8 b = *reinterpret_cast<const bf16v8*>(
                W1T + (size_t)((2 * wv + tt) * 16 + m) * DIM + ks * 32 + kq * 8);
            acc1[tt] = __builtin_amdgcn_mfma_f32_16x16x32_bf16(a, b, acc1[tt], 0, 0, 0);
        }
    }
#pragma unroll
    for (int tt = 0; tt < 2; ++tt) {
        int col = 32 * wv + tt * 16 + m;
        float bv = (float)b1[col];
#pragma unroll
        for (int r = 0; r < 4; ++r) {
            float v = acc1[tt][r] + bv;
            hh[kq * 4 + r][col] = (bf16_t)(v > 0.f ? v : 0.f);
        }
    }
    __syncthreads();
    f32v4 acc2[2];
    acc2[0] = (f32v4){0.f, 0.f, 0.f, 0.f};
    acc2[1] = (f32v4){0.f, 0.f, 0.f, 0.f};
#pragma unroll
    for (int ks = 0; ks < 4; ++ks) {
        bf16v8 a = *reinterpret_cast<const bf16v8*>(&hh[m][ks * 32 + kq * 8]);
#pragma unroll
        for (int tt = 0; tt < 2; ++tt) {
            bf16v8 b = *reinterpret_cast<const bf16v8*>(
                W2T + (size_t)((2 * wv + tt) * 16 + m) * DIM + ks * 32 + kq * 8);
            acc2[tt] = __builtin_amdgcn_mfma_f32_16x16x32_bf16(a, b, acc2[tt], 0, 0, 0);
        }
    }
    float vals2[2][4];
    {
        float sp[4] = {0.f, 0.f, 0.f, 0.f};
#pragma unroll
        for (int tt = 0; tt < 2; ++tt) {
            int col = 32 * wv + tt * 16 + m;
            float bv = (float)b2[col];
#pragma unroll
            for (int r = 0; r < 4; ++r) {
                float v = acc2[tt][r] + bv + (float)xm[kq * 4 + r][col];
                vals2[tt][r] = v;
                sp[r] += v * v;
            }
        }
#pragma unroll
        for (int r = 0; r < 4; ++r) {
            sp[r] += __shfl_xor(sp[r], 1); sp[r] += __shfl_xor(sp[r], 2);
            sp[r] += __shfl_xor(sp[r], 4); sp[r] += __shfl_xor(sp[r], 8);
            if (m == r) ssq_p[kq * 4 + r][wv] = sp[r];
        }
    }
    __syncthreads();
    float o2[2][4];
#pragma unroll
    for (int r = 0; r < 4; ++r) {
        int row = kq * 4 + r;
        int gr = tile * 16 + row;
        float s = ssq_p[row][0] + ssq_p[row][1] + ssq_p[row][2] + ssq_p[row][3];
        float scale = rsqrtf(s * (1.f / 128.f) + EPS_RMS);
#pragma unroll
        for (int tt = 0; tt < 2; ++tt) {
            int col = 32 * wv + tt * 16 + m;
            float o = vals2[tt][r] * scale * (float)n2w[col];
            o2[tt][r] = o;
            if (MODE == 1) ((float*)out)[(size_t)gr * DIM + col] = o;
            else {
                ((bf16_t*)out)[(size_t)gr * DIM + col] = (bf16_t)o;
                x8_n[(size_t)gr * DIM + col] = enc_fp8(o);
            }
        }
    }
    if (MODE == 0) {
        float vs0[NH], vs1[NH], vd0[NH], vd1[NH];
        int col0 = 32 * wv + m, col1 = col0 + 16;
#pragma unroll
        for (int h = 0; h < NH; ++h) {
            vs0[h] = vS[h * DIM + col0]; vs1[h] = vS[h * DIM + col1];
            vd0[h] = vD[h * DIM + col0]; vd1[h] = vD[h * DIM + col1];
        }
#pragma unroll
        for (int r = 0; r < 4; ++r) {
#pragma unroll
            for (int h = 0; h < NH; ++h) {
                float ps = o2[0][r] * vs0[h] + o2[1][r] * vs1[h];
                float pd = o2[0][r] * vd0[h] + o2[1][r] * vd1[h];
                ps += __shfl_xor(ps, 1); ps += __shfl_xor(ps, 2);
                ps += __shfl_xor(ps, 4); ps += __shfl_xor(ps, 8);
                pd += __shfl_xor(pd, 1); pd += __shfl_xor(pd, 2);
                pd += __shfl_xor(pd, 4); pd += __shfl_xor(pd, 8);
                if (m == r * 4 + h) {
                    asd_p[wv][kq * 4 + r][h * 2 + 0] = ps;
                    asd_p[wv][kq * 4 + r][h * 2 + 1] = pd;
                }
            }
        }
        __syncthreads();
        int t = threadIdx.x;
        if (t < 128) {
            int row = t >> 3, idx = t & 7;
            float s = asd_p[0][row][idx] + asd_p[1][row][idx]
                    + asd_p[2][row][idx] + asd_p[3][row][idx];
            int gr = tile * 16 + row;
            if (idx & 1) a_d_n[gr * 4 + (idx >> 1)] = s;
            else         a_s_n[gr * 4 + (idx >> 1)] = s;
        }
    }
}

// ---------------- launch ----------------
extern "C" void kernel_launch(void* const* d_in, const int* in_sizes, int n_in,
                              void* d_out, int out_size, void* d_ws, size_t ws_size,
                              hipStream_t stream) {
    const void* x_in   = d_in[0];
    const void* W_gat  = d_in[1];
    const void* att_s  = d_in[2];
    const void* att_d  = d_in[3];
    const void* bias_g = d_in[4];
    const void* W1     = d_in[5];
    const void* b1     = d_in[6];
    const void* W2     = d_in[7];
    const void* b2     = d_in[8];
    const void* n1w    = d_in[9];
    const void* n2w    = d_in[10];
    const int*  ei     = (const int*)d_in[11];

    char* ws = (char*)d_ws;
    size_t off = 0;
    auto alloc = [&](size_t bytes) {
        void* p = ws + off;
        off = (off + bytes + 255) & ~(size_t)255;
        return p;
    };
    bf16_t* WmixT   = (bf16_t*)alloc((size_t)LAYERS * HD * DIM * 2);
    bf16_t* W1T     = (bf16_t*)alloc((size_t)LAYERS * DIM * DIM * 2);
    bf16_t* W2T     = (bf16_t*)alloc((size_t)LAYERS * DIM * DIM * 2);
    bf16_t* xb      = (bf16_t*)alloc((size_t)N_NODES * DIM * 2);
    bf16_t* y       = (bf16_t*)alloc((size_t)N_NODES * HD * 2);
    unsigned short* x8a = (unsigned short*)alloc((size_t)N_NODES * DIM);
    unsigned short* x8b = (unsigned short*)alloc((size_t)N_NODES * DIM);
    float*  vS      = (float*)alloc((size_t)LAYERS * HD * 4);
    float*  vD      = (float*)alloc((size_t)LAYERS * HD * 4);
    float*  a_sA    = (float*)alloc((size_t)N_NODES * NH * 4);
    float*  a_dA    = (float*)alloc((size_t)N_NODES * NH * 4);
    float*  a_sB    = (float*)alloc((size_t)N_NODES * NH * 4);
    float*  a_dB    = (float*)alloc((size_t)N_NODES * NH * 4);
    int*    deg     = (int*)alloc((size_t)N_NODES * 4);
    int*    cursor  = (int*)alloc((size_t)N_NODES * 4);
    int*    row_ptr = (int*)alloc((size_t)(N_NODES + 1) * 4);
    int*    csr     = (int*)alloc((size_t)NEDGE * 4);
    bf16_t* bgc     = (bf16_t*)alloc((size_t)LAYERS * DIM * 2);
    bf16_t* b1c     = (bf16_t*)alloc((size_t)LAYERS * DIM * 2);
    bf16_t* b2c     = (bf16_t*)alloc((size_t)LAYERS * DIM * 2);
    bf16_t* n1c     = (bf16_t*)alloc((size_t)LAYERS * DIM * 2);
    bf16_t* n2c     = (bf16_t*)alloc((size_t)LAYERS * DIM * 2);

    hipMemsetAsync(deg, 0, (size_t)N_NODES * 4, stream);

    prep_v<<<(LAYERS * DIM * NH * 2 * 64 + 255) / 256, 256, 0, stream>>>(
        x_in, W_gat, att_s, att_d, vS, vD);

    const int NTOT = N_NODES * DIM + LAYERS * DIM * HD + 2 * LAYERS * DIM * DIM
                   + 5 * LAYERS * DIM;
    const int convBlocks = (NTOT + 255) / 256;
    const int histBlocks = (NEDGE + 255) / 256;
    const int asdBlocks  = (N_NODES + 3) / 4;
    mega_setup<<<convBlocks + histBlocks + asdBlocks, 256, 0, stream>>>(
        x_in, W_gat, W1, W2, bias_g, b1, b2, n1w, n2w,
        xb, WmixT, W1T, W2T, bgc, b1c, b2c, n1c, n2c,
        ei, deg, vS, vD, a_sA, a_dA, x8a, convBlocks, histBlocks);

    scan_kernel<<<1, 1024, 0, stream>>>(deg, row_ptr, cursor);
    fill_kernel<<<(NEDGE + 255) / 256, 256, 0, stream>>>(ei, cursor, csr);

    unsigned short* x8cur[2] = {x8a, x8b};
    float* asCur[2] = {a_sA, a_sB};
    float* adCur[2] = {a_dA, a_dB};
    for (int l = 0; l < LAYERS; ++l) {
        int ci = l & 1, ni = (l + 1) & 1;
        gat_gather<<<(N_NODES * 64 + 255) / 256, 256, 0, stream>>>(
            row_ptr, csr, asCur[ci], adCur[ci], x8cur[ci], y);
        if (l < LAYERS - 1) {
            mix_ffn<0><<<NTILES, 256, 0, stream>>>(
                y, WmixT + (size_t)l * HD * DIM, bgc + (size_t)l * DIM,
                n1c + (size_t)l * DIM, xb,
                W1T + (size_t)l * DIM * DIM, b1c + (size_t)l * DIM,
                W2T + (size_t)l * DIM * DIM, b2c + (size_t)l * DIM,
                n2c + (size_t)l * DIM, xb,
                vS + (size_t)(l + 1) * HD, vD + (size_t)(l + 1) * HD,
                asCur[ni], adCur[ni], (unsigned char*)x8cur[ni]);
        } else {
            mix_ffn<1><<<NTILES, 256, 0, stream>>>(
                y, WmixT + (size_t)l * HD * DIM, bgc + (size_t)l * DIM,
                n1c + (size_t)l * DIM, xb,
                W1T + (size_t)l * DIM * DIM, b1c + (size_t)l * DIM,
                W2T + (size_t)l * DIM * DIM, b2c + (size_t)l * DIM,
                n2c + (size_t)l * DIM, d_out,
                nullptr, nullptr, nullptr, nullptr, nullptr);
        }
    }
}

// Round 12
// 339.927 us; speedup vs baseline: 1.1824x; 1.1824x over previous
//
#include <hip/hip_runtime.h>
#include <hip/hip_bf16.h>

#define N_NODES 20000
#define NEDGE   320000
#define DIM     128
#define NH      4
#define HD      512   // NH*DIM
#define LAYERS  3
#define EPS_RMS 1.1920929e-07f
#define SLOPE   0.2f
#define NTILES  (N_NODES >> 4)   // 1250

typedef __bf16 bf16_t;
typedef __bf16 bf16v2 __attribute__((ext_vector_type(2)));
typedef __bf16 bf16v8 __attribute__((ext_vector_type(8)));
typedef float  f32v4  __attribute__((ext_vector_type(4)));
typedef float  f32v2  __attribute__((ext_vector_type(2)));

__device__ __forceinline__ int clamp_node(int s) {
    return ((unsigned)s >= (unsigned)N_NODES) ? 0 : s;
}
__device__ __forceinline__ float leaky(float e) { return e > 0.f ? e : SLOPE * e; }
__device__ __forceinline__ unsigned char enc_fp8(float v) {
    int p = __builtin_amdgcn_cvt_pk_fp8_f32(v, v, 0, false);
    return (unsigned char)(p & 0xff);
}
__device__ __forceinline__ unsigned short enc_fp8_pair(float a, float b) {
    int p = __builtin_amdgcn_cvt_pk_fp8_f32(a, b, 0, false);
    return (unsigned short)(p & 0xffff);
}

// ---- per-wave dtype detection ----
__device__ __forceinline__ bool wave_detect_bf16(const unsigned short* xh) {
    int lane = threadIdx.x & 63;
    unsigned short hw = xh[2 * lane];
    int e = (hw >> 7) & 0xff;
    unsigned long long b = __ballot(e >= 96 && e <= 140);
    return __popcll(b) >= 48;
}
__device__ __forceinline__ bool wave_detect_i64(const int* ei) {
    int lane = threadIdx.x & 63;
    unsigned long long b = __ballot(ei[2 * lane + 1] != 0);
    return b == 0ULL;
}
__device__ __forceinline__ float raw_elem(const void* in, size_t j, bool isbf) {
    return isbf ? (float)((const bf16_t*)in)[j] : ((const float*)in)[j];
}
__device__ __forceinline__ bf16_t cvt_elem(const void* in, size_t j, bool isbf) {
    return isbf ? ((const bf16_t*)in)[j] : (bf16_t)((const float*)in)[j];
}
__device__ __forceinline__ int edge_src(const int* ei, int e, bool is64) {
    return clamp_node(is64 ? ei[2 * e] : ei[e]);
}
__device__ __forceinline__ int edge_dst(const int* ei, int e, bool is64) {
    return clamp_node(is64 ? ei[2 * NEDGE + 2 * e] : ei[NEDGE + e]);
}

// ---------------- prep_v: v_s/v_d[l][h][k] = sum_c Wg[l][k][h*128+c] * att[l][h][c] ----------------
__global__ __launch_bounds__(256) void prep_v(const void* x, const void* Wg,
                                              const void* aS, const void* aD,
                                              float* __restrict__ vS, float* __restrict__ vD) {
    bool isbf = wave_detect_bf16((const unsigned short*)x);
    int w = (int)((blockIdx.x * blockDim.x + threadIdx.x) >> 6);
    if (w >= LAYERS * DIM * NH * 2) return;
    int lane = threadIdx.x & 63;
    int sd = w & 1, h = (w >> 1) & 3, k = (w >> 3) & 127, l = w >> 10;
    const void* att = sd ? aD : aS;
    size_t wbase = (size_t)l * DIM * HD + (size_t)k * HD + h * DIM;
    size_t abase = (size_t)l * NH * DIM + (size_t)h * DIM;
    int c = 2 * lane;
    float p = raw_elem(Wg, wbase + c, isbf) * raw_elem(att, abase + c, isbf)
            + raw_elem(Wg, wbase + c + 1, isbf) * raw_elem(att, abase + c + 1, isbf);
#pragma unroll
    for (int msk = 1; msk < 64; msk <<= 1) p += __shfl_xor(p, msk);
    if (lane == 0) {
        float* dst = sd ? vD : vS;
        dst[l * HD + h * DIM + k] = p;
    }
}

// ---------------- mega: convert(+fragment-pack) + hist + asd_x8 ----------------
__global__ __launch_bounds__(256) void mega_setup(
        const void* x, const void* Wg, const void* W1, const void* W2,
        const void* bg, const void* b1, const void* b2, const void* n1, const void* n2,
        bf16_t* xb, bf16_t* WmixP, bf16_t* W1P, bf16_t* W2P,
        bf16_t* bgc, bf16_t* b1c, bf16_t* b2c, bf16_t* n1c, bf16_t* n2c,
        const int* ei, int* deg,
        const float* vS, const float* vD,
        float* a_s, float* a_d, unsigned short* x8,
        int convBlocks, int histBlocks) {
    const int NX  = N_NODES * DIM;
    const int NWG = LAYERS * DIM * HD;    // 3*65536
    const int NW1 = LAYERS * DIM * DIM;   // 3*16384
    const int NV  = LAYERS * DIM;
    int b = (int)blockIdx.x;
    if (b >= convBlocks + histBlocks) {   // asd_x8 part: wave per node
        bool isbf = wave_detect_bf16((const unsigned short*)x);
        int lane = threadIdx.x & 63;
        int n = (b - convBlocks - histBlocks) * 4 + (int)(threadIdx.x >> 6);
        if (n >= N_NODES) return;
        int c = 2 * lane;
        float f0 = raw_elem(x, (size_t)n * DIM + c, isbf);
        float f1 = raw_elem(x, (size_t)n * DIM + c + 1, isbf);
        x8[n * 64 + lane] = enc_fp8_pair(f0, f1);
#pragma unroll
        for (int h = 0; h < NH; ++h) {
            float ps = f0 * vS[h * DIM + c] + f1 * vS[h * DIM + c + 1];
            float pd = f0 * vD[h * DIM + c] + f1 * vD[h * DIM + c + 1];
#pragma unroll
            for (int msk = 1; msk < 64; msk <<= 1) {
                ps += __shfl_xor(ps, msk);
                pd += __shfl_xor(pd, msk);
            }
            if (lane == 0) {
                a_s[n * 4 + h] = ps;
                a_d[n * 4 + h] = pd;
            }
        }
        return;
    }
    if (b >= convBlocks) {   // histogram
        bool is64 = wave_detect_i64(ei);
        int e = (b - convBlocks) * 256 + threadIdx.x;
        if (e < NEDGE) atomicAdd(&deg[edge_dst(ei, e, is64)], 1);
        return;
    }
    bool isbf = wave_detect_bf16((const unsigned short*)x);
    int i = b * 256 + threadIdx.x;
    if (i < NX) { xb[i] = cvt_elem(x, i, isbf); return; }
    i -= NX;
    if (i < NWG) {   // Wmix fragment-packed: chunk=(wv*16+kk)*2+tt, lane, j
        int l = i >> 16;
        int r = i & 65535;
        int j = r & 7;
        int lane2 = (r >> 3) & 63;
        int mm = lane2 & 15, kqq = lane2 >> 4;
        int tt = (r >> 9) & 1;
        int kk = (r >> 10) & 15;
        int wvv = r >> 14;
        int kidx = kk * 32 + kqq * 8 + j;          // y-dim 0..511
        int h = kidx >> 7, kp = kidx & 127;        // head, source-dim
        int c = 32 * wvv + tt * 16 + mm;           // output col
        WmixP[i] = cvt_elem(Wg, (size_t)l * DIM * HD + (size_t)kp * HD + h * DIM + c, isbf);
        return;
    }
    i -= NWG;
    if (i < NW1) {   // W1 fragment-packed: chunk=(wv*4+ks)*2+tt
        int l = i / 16384;
        int r = i & 16383;
        int j = r & 7;
        int lane2 = (r >> 3) & 63;
        int mm = lane2 & 15, kqq = lane2 >> 4;
        int tt = (r >> 9) & 1;
        int ks = (r >> 10) & 3;
        int wvv = r >> 12;
        int k = ks * 32 + kqq * 8 + j;
        int c = 32 * wvv + tt * 16 + mm;
        W1P[i] = cvt_elem(W1, (size_t)l * DIM * DIM + (size_t)k * DIM + c, isbf);
        return;
    }
    i -= NW1;
    if (i < NW1) {   // W2 fragment-packed
        int l = i / 16384;
        int r = i & 16383;
        int j = r & 7;
        int lane2 = (r >> 3) & 63;
        int mm = lane2 & 15, kqq = lane2 >> 4;
        int tt = (r >> 9) & 1;
        int ks = (r >> 10) & 3;
        int wvv = r >> 12;
        int k = ks * 32 + kqq * 8 + j;
        int c = 32 * wvv + tt * 16 + mm;
        W2P[i] = cvt_elem(W2, (size_t)l * DIM * DIM + (size_t)k * DIM + c, isbf);
        return;
    }
    i -= NW1;
    if (i >= 5 * NV) return;
    int seg = i / NV, k = i - seg * NV;
    if (seg == 0) bgc[k] = cvt_elem(bg, k, isbf);
    else if (seg == 1) b1c[k] = cvt_elem(b1, k, isbf);
    else if (seg == 2) b2c[k] = cvt_elem(b2, k, isbf);
    else if (seg == 3) n1c[k] = cvt_elem(n1, k, isbf);
    else n2c[k] = cvt_elem(n2, k, isbf);
}

__global__ __launch_bounds__(1024) void scan_kernel(const int* __restrict__ deg,
                                                    int* __restrict__ row_ptr,
                                                    int* __restrict__ cursor) {
    __shared__ int wsum[16];
    __shared__ int carry_s;
    int tid = threadIdx.x, lane = tid & 63, wv = tid >> 6;
    if (tid == 0) { carry_s = 0; row_ptr[0] = 0; }
    __syncthreads();
    for (int base = 0; base < N_NODES; base += 1024) {
        int idx = base + tid;
        int v = (idx < N_NODES) ? deg[idx] : 0;
        int x = v;
#pragma unroll
        for (int off = 1; off < 64; off <<= 1) {
            int t = __shfl_up(x, off);
            if (lane >= off) x += t;
        }
        if (lane == 63) wsum[wv] = x;
        __syncthreads();
        if (wv == 0) {
            int s = (lane < 16) ? wsum[lane] : 0;
#pragma unroll
            for (int off = 1; off < 16; off <<= 1) {
                int t = __shfl_up(s, off);
                if (lane >= off) s += t;
            }
            if (lane < 16) wsum[lane] = s;
        }
        __syncthreads();
        int woff = (wv == 0) ? 0 : wsum[wv - 1];
        int c = carry_s;
        int incl = x + woff + c;
        if (idx < N_NODES) {
            row_ptr[idx + 1] = incl;
            cursor[idx] = incl - v;
        }
        __syncthreads();
        if (tid == 1023) carry_s = incl;
        __syncthreads();
    }
}

// fill: csr_src, csr_dst, and layer-0 edge weights w4[pos]
__global__ void fill_kernel(const int* __restrict__ ei, int* __restrict__ cursor,
                            int* __restrict__ csr_src, int* __restrict__ csr_dst,
                            const float* __restrict__ a_s, const float* __restrict__ a_d,
                            float4* __restrict__ w4) {
    bool is64 = wave_detect_i64(ei);
    int e = blockIdx.x * blockDim.x + threadIdx.x;
    if (e < NEDGE) {
        int d = edge_dst(ei, e, is64);
        int s = edge_src(ei, e, is64);
        int pos = atomicAdd(&cursor[d], 1);
        if ((unsigned)pos < (unsigned)NEDGE) {
            csr_src[pos] = s;
            csr_dst[pos] = d;
            float4 av = reinterpret_cast<const float4*>(a_s)[s];
            float4 dv = reinterpret_cast<const float4*>(a_d)[d];
            w4[pos] = {__expf(leaky(av.x + dv.x)), __expf(leaky(av.y + dv.y)),
                       __expf(leaky(av.z + dv.z)), __expf(leaky(av.w + dv.w))};
        }
    }
}

// edge weights for layers 1,2 (edge-parallel, lane-parallel)
__global__ void edge_w(const int* __restrict__ csr_src, const int* __restrict__ csr_dst,
                       const float* __restrict__ a_s, const float* __restrict__ a_d,
                       float4* __restrict__ w4) {
    int p = blockIdx.x * blockDim.x + threadIdx.x;
    if (p >= NEDGE) return;
    int s = clamp_node(csr_src[p]);
    int d = clamp_node(csr_dst[p]);
    float4 av = reinterpret_cast<const float4*>(a_s)[s];
    float4 dv = reinterpret_cast<const float4*>(a_d)[d];
    w4[p] = {__expf(leaky(av.x + dv.x)), __expf(leaky(av.y + dv.y)),
             __expf(leaky(av.z + dv.z)), __expf(leaky(av.w + dv.w))};
}

// ---------------- gat_gather (precomputed edge weights, single-pass, one wave/node) ----------------
__global__ __launch_bounds__(256) void gat_gather(const int* __restrict__ row_ptr,
                                                  const int* __restrict__ csr_src,
                                                  const float4* __restrict__ w4buf,
                                                  const float* __restrict__ a_s,
                                                  const float* __restrict__ a_d,
                                                  const unsigned short* __restrict__ x8,
                                                  bf16_t* __restrict__ y) {
    int n = (int)((blockIdx.x * blockDim.x + threadIdx.x) >> 6);
    if (n >= N_NODES) return;
    int lane = threadIdx.x & 63;
    int beg = row_ptr[n];
    int deg = row_ptr[n + 1] - beg;
    if (deg < 0) deg = 0;
    if (deg > NEDGE) deg = NEDGE;
    if (beg < 0) beg = 0;
    if (beg > NEDGE - deg) beg = NEDGE - deg;

    const float4* a_s4 = reinterpret_cast<const float4*>(a_s);
    const float4 adv = reinterpret_cast<const float4*>(a_d)[n];
    const float4 avs = a_s4[n];
    unsigned short pself = x8[n * 64 + lane];
    int s_reg = (lane < deg) ? clamp_node(csr_src[beg + lane]) : n;

    float4 ws = {__expf(leaky(avs.x + adv.x)), __expf(leaky(avs.y + adv.y)),
                 __expf(leaky(avs.z + adv.z)), __expf(leaky(avs.w + adv.w))};
    float4 z4 = ws;
    float acc[8];
    {
        f32v2 f = __builtin_amdgcn_cvt_pk_f32_fp8((int)pself, false);
        acc[0] = ws.x * f[0]; acc[1] = ws.x * f[1];
        acc[2] = ws.y * f[0]; acc[3] = ws.y * f[1];
        acc[4] = ws.z * f[0]; acc[5] = ws.z * f[1];
        acc[6] = ws.w * f[0]; acc[7] = ws.w * f[1];
    }

    for (int b0 = 0; b0 < deg; b0 += 8) {
        int cnt = deg - b0; if (cnt > 8) cnt = 8;
        unsigned short xe[8]; float4 w[8];
#pragma unroll
        for (int u = 0; u < 8; ++u) {
            if (u < cnt) {
                int e = b0 + u;
                int s = (e < 64) ? __shfl(s_reg, e) : clamp_node(csr_src[beg + e]);
                w[u] = w4buf[beg + e];      // contiguous, broadcast line
                xe[u] = x8[s * 64 + lane];  // one 128-B line
            }
        }
#pragma unroll
        for (int u = 0; u < 8; ++u) {
            if (u < cnt) {
                z4.x += w[u].x; z4.y += w[u].y; z4.z += w[u].z; z4.w += w[u].w;
                f32v2 f = __builtin_amdgcn_cvt_pk_f32_fp8((int)xe[u], false);
                acc[0] += w[u].x * f[0]; acc[1] += w[u].x * f[1];
                acc[2] += w[u].y * f[0]; acc[3] += w[u].y * f[1];
                acc[4] += w[u].z * f[0]; acc[5] += w[u].z * f[1];
                acc[6] += w[u].w * f[0]; acc[7] += w[u].w * f[1];
            }
        }
    }
    float4 ih4 = {1.f / z4.x, 1.f / z4.y, 1.f / z4.z, 1.f / z4.w};
    int c = 2 * lane;
#pragma unroll
    for (int h = 0; h < NH; ++h) {
        float ih = h == 0 ? ih4.x : h == 1 ? ih4.y : h == 2 ? ih4.z : ih4.w;
        bf16v2 o;
        o[0] = (bf16_t)(acc[h * 2 + 0] * ih);
        o[1] = (bf16_t)(acc[h * 2 + 1] * ih);
        *reinterpret_cast<bf16v2*>(&y[(size_t)n * HD + h * DIM + c]) = o;
    }
}

// ---------------- mix_ffn: block = 16 nodes; LDS y-tile + fragment-packed weights ----------------
// MODE 0: writes bf16 xb + next-layer x8/a_s/a_d.  MODE 1: writes f32 d_out.
template <int MODE>
__global__ __launch_bounds__(256) void mix_ffn(
        const bf16_t* __restrict__ y,
        const bf16_t* __restrict__ WmixP, const bf16_t* __restrict__ bg,
        const bf16_t* __restrict__ n1w, const bf16_t* __restrict__ xb,
        const bf16_t* __restrict__ W1P, const bf16_t* __restrict__ b1,
        const bf16_t* __restrict__ W2P, const bf16_t* __restrict__ b2,
        const bf16_t* __restrict__ n2w, void* __restrict__ out,
        const float* __restrict__ vS, const float* __restrict__ vD,
        float* __restrict__ a_s_n, float* __restrict__ a_d_n,
        unsigned char* __restrict__ x8_n) {
    __shared__ bf16_t ylds[16][524];   // pad 524 -> ~2-way max on frag reads
    __shared__ bf16_t xm[16][140];     // pad 140 -> ~2-way
    __shared__ float  ssq_p[16][4];
    __shared__ float  asd_p[4][16][8];
    bf16_t (*hh)[140] = reinterpret_cast<bf16_t (*)[140]>(&ylds[0][0]);  // ylds dead after mix A-reads

    int tile = blockIdx.x;
    int wv = threadIdx.x >> 6;
    int lane = threadIdx.x & 63;
    int m = lane & 15, kq = lane >> 4;

    // stage y-tile (coalesced 16 KB)
    const bf16_t* ybase = y + (size_t)tile * 16 * HD;
#pragma unroll
    for (int it = 0; it < 8; ++it) {
        int f = it * 2048 + (int)threadIdx.x * 8;
        int row = f >> 9, col = f & 511;
        *reinterpret_cast<bf16v8*>(&ylds[row][col]) =
            *reinterpret_cast<const bf16v8*>(ybase + f);
    }
    __syncthreads();

    // ---- mix: wave wv -> cols [32wv,32wv+32), K=512 ----
    f32v4 accm[2];
    accm[0] = (f32v4){0.f, 0.f, 0.f, 0.f};
    accm[1] = (f32v4){0.f, 0.f, 0.f, 0.f};
#pragma unroll
    for (int kk = 0; kk < 16; ++kk) {
        bf16v8 a = *reinterpret_cast<const bf16v8*>(&ylds[m][kk * 32 + kq * 8]);
#pragma unroll
        for (int tt = 0; tt < 2; ++tt) {
            bf16v8 b = *reinterpret_cast<const bf16v8*>(
                WmixP + ((((wv * 16 + kk) * 2 + tt) << 9) + lane * 8));
            accm[tt] = __builtin_amdgcn_mfma_f32_16x16x32_bf16(a, b, accm[tt], 0, 0, 0);
        }
    }
    float vals[2][4];
    {
        float sp[4] = {0.f, 0.f, 0.f, 0.f};
#pragma unroll
        for (int tt = 0; tt < 2; ++tt) {
            int col = 32 * wv + tt * 16 + m;
            float bv = (float)bg[col];
#pragma unroll
            for (int r = 0; r < 4; ++r) {
                int gr = tile * 16 + kq * 4 + r;
                float v = 0.25f * accm[tt][r] + bv + (float)xb[(size_t)gr * DIM + col];
                vals[tt][r] = v;
                sp[r] += v * v;
            }
        }
#pragma unroll
        for (int r = 0; r < 4; ++r) {
            sp[r] += __shfl_xor(sp[r], 1); sp[r] += __shfl_xor(sp[r], 2);
            sp[r] += __shfl_xor(sp[r], 4); sp[r] += __shfl_xor(sp[r], 8);
            if (m == r) ssq_p[kq * 4 + r][wv] = sp[r];
        }
    }
    __syncthreads();
    {
#pragma unroll
        for (int r = 0; r < 4; ++r) {
            int row = kq * 4 + r;
            float s = ssq_p[row][0] + ssq_p[row][1] + ssq_p[row][2] + ssq_p[row][3];
            float scale = rsqrtf(s * (1.f / 128.f) + EPS_RMS);
#pragma unroll
            for (int tt = 0; tt < 2; ++tt) {
                int col = 32 * wv + tt * 16 + m;
                xm[row][col] = (bf16_t)(vals[tt][r] * scale * (float)n1w[col]);
            }
        }
    }
    __syncthreads();

    // ---- FFN1 ----
    f32v4 acc1[2];
    acc1[0] = (f32v4){0.f, 0.f, 0.f, 0.f};
    acc1[1] = (f32v4){0.f, 0.f, 0.f, 0.f};
#pragma unroll
    for (int ks = 0; ks < 4; ++ks) {
        bf16v8 a = *reinterpret_cast<const bf16v8*>(&xm[m][ks * 32 + kq * 8]);
#pragma unroll
        for (int tt = 0; tt < 2; ++tt) {
            bf16v8 b = *reinterpret_cast<const bf16v8*>(
                W1P + ((((wv * 4 + ks) * 2 + tt) << 9) + lane * 8));
            acc1[tt] = __builtin_amdgcn_mfma_f32_16x16x32_bf16(a, b, acc1[tt], 0, 0, 0);
        }
    }
#pragma unroll
    for (int tt = 0; tt < 2; ++tt) {
        int col = 32 * wv + tt * 16 + m;
        float bv = (float)b1[col];
#pragma unroll
        for (int r = 0; r < 4; ++r) {
            float v = acc1[tt][r] + bv;
            hh[kq * 4 + r][col] = (bf16_t)(v > 0.f ? v : 0.f);
        }
    }
    __syncthreads();
    // ---- FFN2 ----
    f32v4 acc2[2];
    acc2[0] = (f32v4){0.f, 0.f, 0.f, 0.f};
    acc2[1] = (f32v4){0.f, 0.f, 0.f, 0.f};
#pragma unroll
    for (int ks = 0; ks < 4; ++ks) {
        bf16v8 a = *reinterpret_cast<const bf16v8*>(&hh[m][ks * 32 + kq * 8]);
#pragma unroll
        for (int tt = 0; tt < 2; ++tt) {
            bf16v8 b = *reinterpret_cast<const bf16v8*>(
                W2P + ((((wv * 4 + ks) * 2 + tt) << 9) + lane * 8));
            acc2[tt] = __builtin_amdgcn_mfma_f32_16x16x32_bf16(a, b, acc2[tt], 0, 0, 0);
        }
    }
    float vals2[2][4];
    {
        float sp[4] = {0.f, 0.f, 0.f, 0.f};
#pragma unroll
        for (int tt = 0; tt < 2; ++tt) {
            int col = 32 * wv + tt * 16 + m;
            float bv = (float)b2[col];
#pragma unroll
            for (int r = 0; r < 4; ++r) {
                float v = acc2[tt][r] + bv + (float)xm[kq * 4 + r][col];
                vals2[tt][r] = v;
                sp[r] += v * v;
            }
        }
#pragma unroll
        for (int r = 0; r < 4; ++r) {
            sp[r] += __shfl_xor(sp[r], 1); sp[r] += __shfl_xor(sp[r], 2);
            sp[r] += __shfl_xor(sp[r], 4); sp[r] += __shfl_xor(sp[r], 8);
            if (m == r) ssq_p[kq * 4 + r][wv] = sp[r];
        }
    }
    __syncthreads();
    float o2[2][4];
#pragma unroll
    for (int r = 0; r < 4; ++r) {
        int row = kq * 4 + r;
        int gr = tile * 16 + row;
        float s = ssq_p[row][0] + ssq_p[row][1] + ssq_p[row][2] + ssq_p[row][3];
        float scale = rsqrtf(s * (1.f / 128.f) + EPS_RMS);
#pragma unroll
        for (int tt = 0; tt < 2; ++tt) {
            int col = 32 * wv + tt * 16 + m;
            float o = vals2[tt][r] * scale * (float)n2w[col];
            o2[tt][r] = o;
            if (MODE == 1) ((float*)out)[(size_t)gr * DIM + col] = o;
            else {
                ((bf16_t*)out)[(size_t)gr * DIM + col] = (bf16_t)o;
                x8_n[(size_t)gr * DIM + col] = enc_fp8(o);
            }
        }
    }
    if (MODE == 0) {
        float vs0[NH], vs1[NH], vd0[NH], vd1[NH];
        int col0 = 32 * wv + m, col1 = col0 + 16;
#pragma unroll
        for (int h = 0; h < NH; ++h) {
            vs0[h] = vS[h * DIM + col0]; vs1[h] = vS[h * DIM + col1];
            vd0[h] = vD[h * DIM + col0]; vd1[h] = vD[h * DIM + col1];
        }
#pragma unroll
        for (int r = 0; r < 4; ++r) {
#pragma unroll
            for (int h = 0; h < NH; ++h) {
                float ps = o2[0][r] * vs0[h] + o2[1][r] * vs1[h];
                float pd = o2[0][r] * vd0[h] + o2[1][r] * vd1[h];
                ps += __shfl_xor(ps, 1); ps += __shfl_xor(ps, 2);
                ps += __shfl_xor(ps, 4); ps += __shfl_xor(ps, 8);
                pd += __shfl_xor(pd, 1); pd += __shfl_xor(pd, 2);
                pd += __shfl_xor(pd, 4); pd += __shfl_xor(pd, 8);
                if (m == r * 4 + h) {
                    asd_p[wv][kq * 4 + r][h * 2 + 0] = ps;
                    asd_p[wv][kq * 4 + r][h * 2 + 1] = pd;
                }
            }
        }
        __syncthreads();
        int t = threadIdx.x;
        if (t < 128) {
            int row = t >> 3, idx = t & 7;
            float s = asd_p[0][row][idx] + asd_p[1][row][idx]
                    + asd_p[2][row][idx] + asd_p[3][row][idx];
            int gr = tile * 16 + row;
            if (idx & 1) a_d_n[gr * 4 + (idx >> 1)] = s;
            else         a_s_n[gr * 4 + (idx >> 1)] = s;
        }
    }
}

// ---------------- launch ----------------
extern "C" void kernel_launch(void* const* d_in, const int* in_sizes, int n_in,
                              void* d_out, int out_size, void* d_ws, size_t ws_size,
                              hipStream_t stream) {
    const void* x_in   = d_in[0];
    const void* W_gat  = d_in[1];
    const void* att_s  = d_in[2];
    const void* att_d  = d_in[3];
    const void* bias_g = d_in[4];
    const void* W1     = d_in[5];
    const void* b1     = d_in[6];
    const void* W2     = d_in[7];
    const void* b2     = d_in[8];
    const void* n1w    = d_in[9];
    const void* n2w    = d_in[10];
    const int*  ei     = (const int*)d_in[11];

    char* ws = (char*)d_ws;
    size_t off = 0;
    auto alloc = [&](size_t bytes) {
        void* p = ws + off;
        off = (off + bytes + 255) & ~(size_t)255;
        return p;
    };
    bf16_t* WmixP   = (bf16_t*)alloc((size_t)LAYERS * HD * DIM * 2);
    bf16_t* W1P     = (bf16_t*)alloc((size_t)LAYERS * DIM * DIM * 2);
    bf16_t* W2P     = (bf16_t*)alloc((size_t)LAYERS * DIM * DIM * 2);
    bf16_t* xb      = (bf16_t*)alloc((size_t)N_NODES * DIM * 2);
    bf16_t* y       = (bf16_t*)alloc((size_t)N_NODES * HD * 2);
    unsigned short* x8a = (unsigned short*)alloc((size_t)N_NODES * DIM);
    unsigned short* x8b = (unsigned short*)alloc((size_t)N_NODES * DIM);
    float*  vS      = (float*)alloc((size_t)LAYERS * HD * 4);
    float*  vD      = (float*)alloc((size_t)LAYERS * HD * 4);
    float*  a_sA    = (float*)alloc((size_t)N_NODES * NH * 4);
    float*  a_dA    = (float*)alloc((size_t)N_NODES * NH * 4);
    float*  a_sB    = (float*)alloc((size_t)N_NODES * NH * 4);
    float*  a_dB    = (float*)alloc((size_t)N_NODES * NH * 4);
    int*    deg     = (int*)alloc((size_t)N_NODES * 4);
    int*    cursor  = (int*)alloc((size_t)N_NODES * 4);
    int*    row_ptr = (int*)alloc((size_t)(N_NODES + 1) * 4);
    int*    csr     = (int*)alloc((size_t)NEDGE * 4);
    int*    csrd    = (int*)alloc((size_t)NEDGE * 4);
    float4* w4      = (float4*)alloc((size_t)NEDGE * 16);
    bf16_t* bgc     = (bf16_t*)alloc((size_t)LAYERS * DIM * 2);
    bf16_t* b1c     = (bf16_t*)alloc((size_t)LAYERS * DIM * 2);
    bf16_t* b2c     = (bf16_t*)alloc((size_t)LAYERS * DIM * 2);
    bf16_t* n1c     = (bf16_t*)alloc((size_t)LAYERS * DIM * 2);
    bf16_t* n2c     = (bf16_t*)alloc((size_t)LAYERS * DIM * 2);

    hipMemsetAsync(deg, 0, (size_t)N_NODES * 4, stream);

    prep_v<<<(LAYERS * DIM * NH * 2 * 64 + 255) / 256, 256, 0, stream>>>(
        x_in, W_gat, att_s, att_d, vS, vD);

    const int NTOT = N_NODES * DIM + LAYERS * DIM * HD + 2 * LAYERS * DIM * DIM
                   + 5 * LAYERS * DIM;
    const int convBlocks = (NTOT + 255) / 256;
    const int histBlocks = (NEDGE + 255) / 256;
    const int asdBlocks  = (N_NODES + 3) / 4;
    mega_setup<<<convBlocks + histBlocks + asdBlocks, 256, 0, stream>>>(
        x_in, W_gat, W1, W2, bias_g, b1, b2, n1w, n2w,
        xb, WmixP, W1P, W2P, bgc, b1c, b2c, n1c, n2c,
        ei, deg, vS, vD, a_sA, a_dA, x8a, convBlocks, histBlocks);

    scan_kernel<<<1, 1024, 0, stream>>>(deg, row_ptr, cursor);
    fill_kernel<<<(NEDGE + 255) / 256, 256, 0, stream>>>(ei, cursor, csr, csrd, a_sA, a_dA, w4);

    unsigned short* x8cur[2] = {x8a, x8b};
    float* asCur[2] = {a_sA, a_sB};
    float* adCur[2] = {a_dA, a_dB};
    for (int l = 0; l < LAYERS; ++l) {
        int ci = l & 1, ni = (l + 1) & 1;
        gat_gather<<<(N_NODES * 64 + 255) / 256, 256, 0, stream>>>(
            row_ptr, csr, w4, asCur[ci], adCur[ci], x8cur[ci], y);
        if (l < LAYERS - 1) {
            mix_ffn<0><<<NTILES, 256, 0, stream>>>(
                y, WmixP + (size_t)l * HD * DIM, bgc + (size_t)l * DIM,
                n1c + (size_t)l * DIM, xb,
                W1P + (size_t)l * DIM * DIM, b1c + (size_t)l * DIM,
                W2P + (size_t)l * DIM * DIM, b2c + (size_t)l * DIM,
                n2c + (size_t)l * DIM, xb,
                vS + (size_t)(l + 1) * HD, vD + (size_t)(l + 1) * HD,
                asCur[ni], adCur[ni], (unsigned char*)x8cur[ni]);
            edge_w<<<(NEDGE + 255) / 256, 256, 0, stream>>>(
                csr, csrd, asCur[ni], adCur[ni], w4);
        } else {
            mix_ffn<1><<<NTILES, 256, 0, stream>>>(
                y, WmixP + (size_t)l * HD * DIM, bgc + (size_t)l * DIM,
                n1c + (size_t)l * DIM, xb,
                W1P + (size_t)l * DIM * DIM, b1c + (size_t)l * DIM,
                W2P + (size_t)l * DIM * DIM, b2c + (size_t)l * DIM,
                n2c + (size_t)l * DIM, d_out,
                nullptr, nullptr, nullptr, nullptr, nullptr);
        }
    }
}

// Round 13
// 339.852 us; speedup vs baseline: 1.1827x; 1.0002x over previous
//
#include <hip/hip_runtime.h>
#include <hip/hip_bf16.h>

#define N_NODES 20000
#define NEDGE   320000
#define DIM     128
#define NH      4
#define HD      512   // NH*DIM
#define LAYERS  3
#define EPS_RMS 1.1920929e-07f
#define SLOPE   0.2f
#define NTILES  (N_NODES >> 4)   // 1250

typedef __bf16 bf16_t;
typedef __bf16 bf16v2 __attribute__((ext_vector_type(2)));
typedef __bf16 bf16v8 __attribute__((ext_vector_type(8)));
typedef float  f32v4  __attribute__((ext_vector_type(4)));
typedef float  f32v2  __attribute__((ext_vector_type(2)));

__device__ __forceinline__ int clamp_node(int s) {
    return ((unsigned)s >= (unsigned)N_NODES) ? 0 : s;
}
__device__ __forceinline__ float leaky(float e) { return e > 0.f ? e : SLOPE * e; }
__device__ __forceinline__ unsigned char enc_fp8(float v) {
    int p = __builtin_amdgcn_cvt_pk_fp8_f32(v, v, 0, false);
    return (unsigned char)(p & 0xff);
}
__device__ __forceinline__ unsigned short enc_fp8_pair(float a, float b) {
    int p = __builtin_amdgcn_cvt_pk_fp8_f32(a, b, 0, false);
    return (unsigned short)(p & 0xffff);
}

// ---- per-wave dtype detection ----
__device__ __forceinline__ bool wave_detect_bf16(const unsigned short* xh) {
    int lane = threadIdx.x & 63;
    unsigned short hw = xh[2 * lane];
    int e = (hw >> 7) & 0xff;
    unsigned long long b = __ballot(e >= 96 && e <= 140);
    return __popcll(b) >= 48;
}
__device__ __forceinline__ bool wave_detect_i64(const int* ei) {
    int lane = threadIdx.x & 63;
    unsigned long long b = __ballot(ei[2 * lane + 1] != 0);
    return b == 0ULL;
}
__device__ __forceinline__ float raw_elem(const void* in, size_t j, bool isbf) {
    return isbf ? (float)((const bf16_t*)in)[j] : ((const float*)in)[j];
}
__device__ __forceinline__ bf16_t cvt_elem(const void* in, size_t j, bool isbf) {
    return isbf ? ((const bf16_t*)in)[j] : (bf16_t)((const float*)in)[j];
}
__device__ __forceinline__ int edge_src(const int* ei, int e, bool is64) {
    return clamp_node(is64 ? ei[2 * e] : ei[e]);
}
__device__ __forceinline__ int edge_dst(const int* ei, int e, bool is64) {
    return clamp_node(is64 ? ei[2 * NEDGE + 2 * e] : ei[NEDGE + e]);
}

// ---------------- prep_v (+ deg zeroing): v_s/v_d[l][h][k] = Wg[l][k][h*128+:]·att[l][h][:] ----------------
__global__ __launch_bounds__(256) void prep_v(const void* x, const void* Wg,
                                              const void* aS, const void* aD,
                                              float* __restrict__ vS, float* __restrict__ vD,
                                              int* __restrict__ deg) {
    int gid = blockIdx.x * 256 + threadIdx.x;
    for (int i = gid; i < N_NODES; i += gridDim.x * 256) deg[i] = 0;
    bool isbf = wave_detect_bf16((const unsigned short*)x);
    int w = gid >> 6;
    if (w >= LAYERS * DIM * NH * 2) return;
    int lane = threadIdx.x & 63;
    int sd = w & 1, h = (w >> 1) & 3, k = (w >> 3) & 127, l = w >> 10;
    const void* att = sd ? aD : aS;
    size_t wbase = (size_t)l * DIM * HD + (size_t)k * HD + h * DIM;
    size_t abase = (size_t)l * NH * DIM + (size_t)h * DIM;
    int c = 2 * lane;
    float p = raw_elem(Wg, wbase + c, isbf) * raw_elem(att, abase + c, isbf)
            + raw_elem(Wg, wbase + c + 1, isbf) * raw_elem(att, abase + c + 1, isbf);
#pragma unroll
    for (int msk = 1; msk < 64; msk <<= 1) p += __shfl_xor(p, msk);
    if (lane == 0) {
        float* dst = sd ? vD : vS;
        dst[l * HD + h * DIM + k] = p;
    }
}

// ---------------- mega: convert(+fragment-pack) + hist + asd_x8 ----------------
__global__ __launch_bounds__(256) void mega_setup(
        const void* x, const void* Wg, const void* W1, const void* W2,
        const void* bg, const void* b1, const void* b2, const void* n1, const void* n2,
        bf16_t* xb, bf16_t* WmixP, bf16_t* W1P, bf16_t* W2P,
        bf16_t* bgc, bf16_t* b1c, bf16_t* b2c, bf16_t* n1c, bf16_t* n2c,
        const int* ei, int* deg,
        const float* vS, const float* vD,
        float* a_s, float* a_d, unsigned short* x8,
        int convBlocks, int histBlocks) {
    const int NX  = N_NODES * DIM;
    const int NWG = LAYERS * DIM * HD;    // 3*65536
    const int NW1 = LAYERS * DIM * DIM;   // 3*16384
    const int NV  = LAYERS * DIM;
    int b = (int)blockIdx.x;
    if (b >= convBlocks + histBlocks) {   // asd_x8 part: wave per node
        bool isbf = wave_detect_bf16((const unsigned short*)x);
        int lane = threadIdx.x & 63;
        int n = (b - convBlocks - histBlocks) * 4 + (int)(threadIdx.x >> 6);
        if (n >= N_NODES) return;
        int c = 2 * lane;
        float f0 = raw_elem(x, (size_t)n * DIM + c, isbf);
        float f1 = raw_elem(x, (size_t)n * DIM + c + 1, isbf);
        x8[n * 64 + lane] = enc_fp8_pair(f0, f1);
#pragma unroll
        for (int h = 0; h < NH; ++h) {
            float ps = f0 * vS[h * DIM + c] + f1 * vS[h * DIM + c + 1];
            float pd = f0 * vD[h * DIM + c] + f1 * vD[h * DIM + c + 1];
#pragma unroll
            for (int msk = 1; msk < 64; msk <<= 1) {
                ps += __shfl_xor(ps, msk);
                pd += __shfl_xor(pd, msk);
            }
            if (lane == 0) {
                a_s[n * 4 + h] = ps;
                a_d[n * 4 + h] = pd;
            }
        }
        return;
    }
    if (b >= convBlocks) {   // histogram
        bool is64 = wave_detect_i64(ei);
        int e = (b - convBlocks) * 256 + threadIdx.x;
        if (e < NEDGE) atomicAdd(&deg[edge_dst(ei, e, is64)], 1);
        return;
    }
    bool isbf = wave_detect_bf16((const unsigned short*)x);
    int i = b * 256 + threadIdx.x;
    if (i < NX) { xb[i] = cvt_elem(x, i, isbf); return; }
    i -= NX;
    if (i < NWG) {   // Wmix fragment-packed: chunk=(wv*16+kk)*2+tt, lane, j
        int l = i >> 16;
        int r = i & 65535;
        int j = r & 7;
        int lane2 = (r >> 3) & 63;
        int mm = lane2 & 15, kqq = lane2 >> 4;
        int tt = (r >> 9) & 1;
        int kk = (r >> 10) & 15;
        int wvv = r >> 14;
        int kidx = kk * 32 + kqq * 8 + j;          // y-dim 0..511
        int h = kidx >> 7, kp = kidx & 127;        // head, source-dim
        int c = 32 * wvv + tt * 16 + mm;           // output col
        WmixP[i] = cvt_elem(Wg, (size_t)l * DIM * HD + (size_t)kp * HD + h * DIM + c, isbf);
        return;
    }
    i -= NWG;
    if (i < NW1) {   // W1 fragment-packed: chunk=(wv*4+ks)*2+tt
        int l = i / 16384;
        int r = i & 16383;
        int j = r & 7;
        int lane2 = (r >> 3) & 63;
        int mm = lane2 & 15, kqq = lane2 >> 4;
        int tt = (r >> 9) & 1;
        int ks = (r >> 10) & 3;
        int wvv = r >> 12;
        int k = ks * 32 + kqq * 8 + j;
        int c = 32 * wvv + tt * 16 + mm;
        W1P[i] = cvt_elem(W1, (size_t)l * DIM * DIM + (size_t)k * DIM + c, isbf);
        return;
    }
    i -= NW1;
    if (i < NW1) {   // W2 fragment-packed
        int l = i / 16384;
        int r = i & 16383;
        int j = r & 7;
        int lane2 = (r >> 3) & 63;
        int mm = lane2 & 15, kqq = lane2 >> 4;
        int tt = (r >> 9) & 1;
        int ks = (r >> 10) & 3;
        int wvv = r >> 12;
        int k = ks * 32 + kqq * 8 + j;
        int c = 32 * wvv + tt * 16 + mm;
        W2P[i] = cvt_elem(W2, (size_t)l * DIM * DIM + (size_t)k * DIM + c, isbf);
        return;
    }
    i -= NW1;
    if (i >= 5 * NV) return;
    int seg = i / NV, k = i - seg * NV;
    if (seg == 0) bgc[k] = cvt_elem(bg, k, isbf);
    else if (seg == 1) b1c[k] = cvt_elem(b1, k, isbf);
    else if (seg == 2) b2c[k] = cvt_elem(b2, k, isbf);
    else if (seg == 3) n1c[k] = cvt_elem(n1, k, isbf);
    else n2c[k] = cvt_elem(n2, k, isbf);
}

__global__ __launch_bounds__(1024) void scan_kernel(const int* __restrict__ deg,
                                                    int* __restrict__ row_ptr,
                                                    int* __restrict__ cursor) {
    __shared__ int wsum[16];
    __shared__ int carry_s;
    int tid = threadIdx.x, lane = tid & 63, wv = tid >> 6;
    if (tid == 0) { carry_s = 0; row_ptr[0] = 0; }
    __syncthreads();
    for (int base = 0; base < N_NODES; base += 1024) {
        int idx = base + tid;
        int v = (idx < N_NODES) ? deg[idx] : 0;
        int x = v;
#pragma unroll
        for (int off = 1; off < 64; off <<= 1) {
            int t = __shfl_up(x, off);
            if (lane >= off) x += t;
        }
        if (lane == 63) wsum[wv] = x;
        __syncthreads();
        if (wv == 0) {
            int s = (lane < 16) ? wsum[lane] : 0;
#pragma unroll
            for (int off = 1; off < 16; off <<= 1) {
                int t = __shfl_up(s, off);
                if (lane >= off) s += t;
            }
            if (lane < 16) wsum[lane] = s;
        }
        __syncthreads();
        int woff = (wv == 0) ? 0 : wsum[wv - 1];
        int c = carry_s;
        int incl = x + woff + c;
        if (idx < N_NODES) {
            row_ptr[idx + 1] = incl;
            cursor[idx] = incl - v;
        }
        __syncthreads();
        if (tid == 1023) carry_s = incl;
        __syncthreads();
    }
}

__global__ void fill_kernel(const int* __restrict__ ei, int* __restrict__ cursor,
                            int* __restrict__ csr_src) {
    bool is64 = wave_detect_i64(ei);
    int e = blockIdx.x * blockDim.x + threadIdx.x;
    if (e < NEDGE) {
        int d = edge_dst(ei, e, is64);
        int pos = atomicAdd(&cursor[d], 1);
        if ((unsigned)pos < (unsigned)NEDGE) csr_src[pos] = edge_src(ei, e, is64);
    }
}

// ---------------- gat_gather: lane-parallel edge weights, single-pass, one wave/node ----------------
// Lane e computes edge e's 4-head weight once (exp w/o max-stab: |e-values| << 1
// analytically, verified R11); main loop broadcasts via shfl. Z via one butterfly.
__global__ __launch_bounds__(256) void gat_gather(const int* __restrict__ row_ptr,
                                                  const int* __restrict__ csr_src,
                                                  const float* __restrict__ a_s,
                                                  const float* __restrict__ a_d,
                                                  const unsigned short* __restrict__ x8,
                                                  bf16_t* __restrict__ y) {
    int n = (int)((blockIdx.x * blockDim.x + threadIdx.x) >> 6);
    if (n >= N_NODES) return;
    int lane = threadIdx.x & 63;
    int beg = row_ptr[n];
    int deg = row_ptr[n + 1] - beg;
    if (deg < 0) deg = 0;
    if (deg > NEDGE) deg = NEDGE;
    if (beg < 0) beg = 0;
    if (beg > NEDGE - deg) beg = NEDGE - deg;

    const float4* a_s4 = reinterpret_cast<const float4*>(a_s);
    const float4 adv = reinterpret_cast<const float4*>(a_d)[n];
    const float4 avs = a_s4[n];
    unsigned short pself = x8[n * 64 + lane];
    int s_reg = 0;
    float4 wlane = {0.f, 0.f, 0.f, 0.f};
    if (lane < deg) {
        s_reg = clamp_node(csr_src[beg + lane]);
        float4 av = a_s4[s_reg];
        wlane = {__expf(leaky(av.x + adv.x)), __expf(leaky(av.y + adv.y)),
                 __expf(leaky(av.z + adv.z)), __expf(leaky(av.w + adv.w))};
    }
    float4 wself = {__expf(leaky(avs.x + adv.x)), __expf(leaky(avs.y + adv.y)),
                    __expf(leaky(avs.z + adv.z)), __expf(leaky(avs.w + adv.w))};
    // Z = wself + sum(wlane over lanes) [+ inline adds for e>=64]
    float4 zr = wlane;
#pragma unroll
    for (int msk = 1; msk < 64; msk <<= 1) {
        zr.x += __shfl_xor(zr.x, msk);
        zr.y += __shfl_xor(zr.y, msk);
        zr.z += __shfl_xor(zr.z, msk);
        zr.w += __shfl_xor(zr.w, msk);
    }
    float4 z4 = {wself.x + zr.x, wself.y + zr.y, wself.z + zr.z, wself.w + zr.w};

    float acc[8];
    {
        f32v2 f = __builtin_amdgcn_cvt_pk_f32_fp8((int)pself, false);
        acc[0] = wself.x * f[0]; acc[1] = wself.x * f[1];
        acc[2] = wself.y * f[0]; acc[3] = wself.y * f[1];
        acc[4] = wself.z * f[0]; acc[5] = wself.z * f[1];
        acc[6] = wself.w * f[0]; acc[7] = wself.w * f[1];
    }

    for (int b0 = 0; b0 < deg; b0 += 8) {
        int cnt = deg - b0; if (cnt > 8) cnt = 8;
        unsigned short xe[8]; float4 w[8];
#pragma unroll
        for (int u = 0; u < 8; ++u) {
            if (u < cnt) {
                int e = b0 + u;
                int s;
                if (e < 64) {
                    s = __shfl(s_reg, e);
                    w[u].x = __shfl(wlane.x, e);
                    w[u].y = __shfl(wlane.y, e);
                    w[u].z = __shfl(wlane.z, e);
                    w[u].w = __shfl(wlane.w, e);
                } else {
                    s = clamp_node(csr_src[beg + e]);
                    float4 av = a_s4[s];
                    w[u] = {__expf(leaky(av.x + adv.x)), __expf(leaky(av.y + adv.y)),
                            __expf(leaky(av.z + adv.z)), __expf(leaky(av.w + adv.w))};
                    z4.x += w[u].x; z4.y += w[u].y; z4.z += w[u].z; z4.w += w[u].w;
                }
                xe[u] = x8[s * 64 + lane];
            }
        }
#pragma unroll
        for (int u = 0; u < 8; ++u) {
            if (u < cnt) {
                f32v2 f = __builtin_amdgcn_cvt_pk_f32_fp8((int)xe[u], false);
                acc[0] += w[u].x * f[0]; acc[1] += w[u].x * f[1];
                acc[2] += w[u].y * f[0]; acc[3] += w[u].y * f[1];
                acc[4] += w[u].z * f[0]; acc[5] += w[u].z * f[1];
                acc[6] += w[u].w * f[0]; acc[7] += w[u].w * f[1];
            }
        }
    }
    float4 ih4 = {1.f / z4.x, 1.f / z4.y, 1.f / z4.z, 1.f / z4.w};
    int c = 2 * lane;
#pragma unroll
    for (int h = 0; h < NH; ++h) {
        float ih = h == 0 ? ih4.x : h == 1 ? ih4.y : h == 2 ? ih4.z : ih4.w;
        bf16v2 o;
        o[0] = (bf16_t)(acc[h * 2 + 0] * ih);
        o[1] = (bf16_t)(acc[h * 2 + 1] * ih);
        *reinterpret_cast<bf16v2*>(&y[(size_t)n * HD + h * DIM + c]) = o;
    }
}

// ---------------- mix_ffn: block = 16 nodes; LDS y-tile + fragment-packed weights ----------------
// MODE 0: writes bf16 xb + next-layer x8/a_s/a_d.  MODE 1: writes f32 d_out.
template <int MODE>
__global__ __launch_bounds__(256) void mix_ffn(
        const bf16_t* __restrict__ y,
        const bf16_t* __restrict__ WmixP, const bf16_t* __restrict__ bg,
        const bf16_t* __restrict__ n1w, const bf16_t* __restrict__ xb,
        const bf16_t* __restrict__ W1P, const bf16_t* __restrict__ b1,
        const bf16_t* __restrict__ W2P, const bf16_t* __restrict__ b2,
        const bf16_t* __restrict__ n2w, void* __restrict__ out,
        const float* __restrict__ vS, const float* __restrict__ vD,
        float* __restrict__ a_s_n, float* __restrict__ a_d_n,
        unsigned char* __restrict__ x8_n) {
    __shared__ bf16_t ylds[16][524];
    __shared__ bf16_t xm[16][140];
    __shared__ float  ssq_p[16][4];
    __shared__ float  asd_p[4][16][8];
    bf16_t (*hh)[140] = reinterpret_cast<bf16_t (*)[140]>(&ylds[0][0]);

    int tile = blockIdx.x;
    int wv = threadIdx.x >> 6;
    int lane = threadIdx.x & 63;
    int m = lane & 15, kq = lane >> 4;

    const bf16_t* ybase = y + (size_t)tile * 16 * HD;
#pragma unroll
    for (int it = 0; it < 8; ++it) {
        int f = it * 2048 + (int)threadIdx.x * 8;
        int row = f >> 9, col = f & 511;
        *reinterpret_cast<bf16v8*>(&ylds[row][col]) =
            *reinterpret_cast<const bf16v8*>(ybase + f);
    }
    __syncthreads();

    f32v4 accm[2];
    accm[0] = (f32v4){0.f, 0.f, 0.f, 0.f};
    accm[1] = (f32v4){0.f, 0.f, 0.f, 0.f};
#pragma unroll
    for (int kk = 0; kk < 16; ++kk) {
        bf16v8 a = *reinterpret_cast<const bf16v8*>(&ylds[m][kk * 32 + kq * 8]);
#pragma unroll
        for (int tt = 0; tt < 2; ++tt) {
            bf16v8 b = *reinterpret_cast<const bf16v8*>(
                WmixP + ((((wv * 16 + kk) * 2 + tt) << 9) + lane * 8));
            accm[tt] = __builtin_amdgcn_mfma_f32_16x16x32_bf16(a, b, accm[tt], 0, 0, 0);
        }
    }
    float vals[2][4];
    {
        float sp[4] = {0.f, 0.f, 0.f, 0.f};
#pragma unroll
        for (int tt = 0; tt < 2; ++tt) {
            int col = 32 * wv + tt * 16 + m;
            float bv = (float)bg[col];
#pragma unroll
            for (int r = 0; r < 4; ++r) {
                int gr = tile * 16 + kq * 4 + r;
                float v = 0.25f * accm[tt][r] + bv + (float)xb[(size_t)gr * DIM + col];
                vals[tt][r] = v;
                sp[r] += v * v;
            }
        }
#pragma unroll
        for (int r = 0; r < 4; ++r) {
            sp[r] += __shfl_xor(sp[r], 1); sp[r] += __shfl_xor(sp[r], 2);
            sp[r] += __shfl_xor(sp[r], 4); sp[r] += __shfl_xor(sp[r], 8);
            if (m == r) ssq_p[kq * 4 + r][wv] = sp[r];
        }
    }
    __syncthreads();
    {
#pragma unroll
        for (int r = 0; r < 4; ++r) {
            int row = kq * 4 + r;
            float s = ssq_p[row][0] + ssq_p[row][1] + ssq_p[row][2] + ssq_p[row][3];
            float scale = rsqrtf(s * (1.f / 128.f) + EPS_RMS);
#pragma unroll
            for (int tt = 0; tt < 2; ++tt) {
                int col = 32 * wv + tt * 16 + m;
                xm[row][col] = (bf16_t)(vals[tt][r] * scale * (float)n1w[col]);
            }
        }
    }
    __syncthreads();

    f32v4 acc1[2];
    acc1[0] = (f32v4){0.f, 0.f, 0.f, 0.f};
    acc1[1] = (f32v4){0.f, 0.f, 0.f, 0.f};
#pragma unroll
    for (int ks = 0; ks < 4; ++ks) {
        bf16v8 a = *reinterpret_cast<const bf16v8*>(&xm[m][ks * 32 + kq * 8]);
#pragma unroll
        for (int tt = 0; tt < 2; ++tt) {
            bf16v8 b = *reinterpret_cast<const bf16v8*>(
                W1P + ((((wv * 4 + ks) * 2 + tt) << 9) + lane * 8));
            acc1[tt] = __builtin_amdgcn_mfma_f32_16x16x32_bf16(a, b, acc1[tt], 0, 0, 0);
        }
    }
#pragma unroll
    for (int tt = 0; tt < 2; ++tt) {
        int col = 32 * wv + tt * 16 + m;
        float bv = (float)b1[col];
#pragma unroll
        for (int r = 0; r < 4; ++r) {
            float v = acc1[tt][r] + bv;
            hh[kq * 4 + r][col] = (bf16_t)(v > 0.f ? v : 0.f);
        }
    }
    __syncthreads();
    f32v4 acc2[2];
    acc2[0] = (f32v4){0.f, 0.f, 0.f, 0.f};
    acc2[1] = (f32v4){0.f, 0.f, 0.f, 0.f};
#pragma unroll
    for (int ks = 0; ks < 4; ++ks) {
        bf16v8 a = *reinterpret_cast<const bf16v8*>(&hh[m][ks * 32 + kq * 8]);
#pragma unroll
        for (int tt = 0; tt < 2; ++tt) {
            bf16v8 b = *reinterpret_cast<const bf16v8*>(
                W2P + ((((wv * 4 + ks) * 2 + tt) << 9) + lane * 8));
            acc2[tt] = __builtin_amdgcn_mfma_f32_16x16x32_bf16(a, b, acc2[tt], 0, 0, 0);
        }
    }
    float vals2[2][4];
    {
        float sp[4] = {0.f, 0.f, 0.f, 0.f};
#pragma unroll
        for (int tt = 0; tt < 2; ++tt) {
            int col = 32 * wv + tt * 16 + m;
            float bv = (float)b2[col];
#pragma unroll
            for (int r = 0; r < 4; ++r) {
                float v = acc2[tt][r] + bv + (float)xm[kq * 4 + r][col];
                vals2[tt][r] = v;
                sp[r] += v * v;
            }
        }
#pragma unroll
        for (int r = 0; r < 4; ++r) {
            sp[r] += __shfl_xor(sp[r], 1); sp[r] += __shfl_xor(sp[r], 2);
            sp[r] += __shfl_xor(sp[r], 4); sp[r] += __shfl_xor(sp[r], 8);
            if (m == r) ssq_p[kq * 4 + r][wv] = sp[r];
        }
    }
    __syncthreads();
    float o2[2][4];
#pragma unroll
    for (int r = 0; r < 4; ++r) {
        int row = kq * 4 + r;
        int gr = tile * 16 + row;
        float s = ssq_p[row][0] + ssq_p[row][1] + ssq_p[row][2] + ssq_p[row][3];
        float scale = rsqrtf(s * (1.f / 128.f) + EPS_RMS);
#pragma unroll
        for (int tt = 0; tt < 2; ++tt) {
            int col = 32 * wv + tt * 16 + m;
            float o = vals2[tt][r] * scale * (float)n2w[col];
            o2[tt][r] = o;
            if (MODE == 1) ((float*)out)[(size_t)gr * DIM + col] = o;
            else {
                ((bf16_t*)out)[(size_t)gr * DIM + col] = (bf16_t)o;
                x8_n[(size_t)gr * DIM + col] = enc_fp8(o);
            }
        }
    }
    if (MODE == 0) {
        float vs0[NH], vs1[NH], vd0[NH], vd1[NH];
        int col0 = 32 * wv + m, col1 = col0 + 16;
#pragma unroll
        for (int h = 0; h < NH; ++h) {
            vs0[h] = vS[h * DIM + col0]; vs1[h] = vS[h * DIM + col1];
            vd0[h] = vD[h * DIM + col0]; vd1[h] = vD[h * DIM + col1];
        }
#pragma unroll
        for (int r = 0; r < 4; ++r) {
#pragma unroll
            for (int h = 0; h < NH; ++h) {
                float ps = o2[0][r] * vs0[h] + o2[1][r] * vs1[h];
                float pd = o2[0][r] * vd0[h] + o2[1][r] * vd1[h];
                ps += __shfl_xor(ps, 1); ps += __shfl_xor(ps, 2);
                ps += __shfl_xor(ps, 4); ps += __shfl_xor(ps, 8);
                pd += __shfl_xor(pd, 1); pd += __shfl_xor(pd, 2);
                pd += __shfl_xor(pd, 4); pd += __shfl_xor(pd, 8);
                if (m == r * 4 + h) {
                    asd_p[wv][kq * 4 + r][h * 2 + 0] = ps;
                    asd_p[wv][kq * 4 + r][h * 2 + 1] = pd;
                }
            }
        }
        __syncthreads();
        int t = threadIdx.x;
        if (t < 128) {
            int row = t >> 3, idx = t & 7;
            float s = asd_p[0][row][idx] + asd_p[1][row][idx]
                    + asd_p[2][row][idx] + asd_p[3][row][idx];
            int gr = tile * 16 + row;
            if (idx & 1) a_d_n[gr * 4 + (idx >> 1)] = s;
            else         a_s_n[gr * 4 + (idx >> 1)] = s;
        }
    }
}

// ---------------- launch (10 dispatches) ----------------
extern "C" void kernel_launch(void* const* d_in, const int* in_sizes, int n_in,
                              void* d_out, int out_size, void* d_ws, size_t ws_size,
                              hipStream_t stream) {
    const void* x_in   = d_in[0];
    const void* W_gat  = d_in[1];
    const void* att_s  = d_in[2];
    const void* att_d  = d_in[3];
    const void* bias_g = d_in[4];
    const void* W1     = d_in[5];
    const void* b1     = d_in[6];
    const void* W2     = d_in[7];
    const void* b2     = d_in[8];
    const void* n1w    = d_in[9];
    const void* n2w    = d_in[10];
    const int*  ei     = (const int*)d_in[11];

    char* ws = (char*)d_ws;
    size_t off = 0;
    auto alloc = [&](size_t bytes) {
        void* p = ws + off;
        off = (off + bytes + 255) & ~(size_t)255;
        return p;
    };
    bf16_t* WmixP   = (bf16_t*)alloc((size_t)LAYERS * HD * DIM * 2);
    bf16_t* W1P     = (bf16_t*)alloc((size_t)LAYERS * DIM * DIM * 2);
    bf16_t* W2P     = (bf16_t*)alloc((size_t)LAYERS * DIM * DIM * 2);
    bf16_t* xb      = (bf16_t*)alloc((size_t)N_NODES * DIM * 2);
    bf16_t* y       = (bf16_t*)alloc((size_t)N_NODES * HD * 2);
    unsigned short* x8a = (unsigned short*)alloc((size_t)N_NODES * DIM);
    unsigned short* x8b = (unsigned short*)alloc((size_t)N_NODES * DIM);
    float*  vS      = (float*)alloc((size_t)LAYERS * HD * 4);
    float*  vD      = (float*)alloc((size_t)LAYERS * HD * 4);
    float*  a_sA    = (float*)alloc((size_t)N_NODES * NH * 4);
    float*  a_dA    = (float*)alloc((size_t)N_NODES * NH * 4);
    float*  a_sB    = (float*)alloc((size_t)N_NODES * NH * 4);
    float*  a_dB    = (float*)alloc((size_t)N_NODES * NH * 4);
    int*    deg     = (int*)alloc((size_t)N_NODES * 4);
    int*    cursor  = (int*)alloc((size_t)N_NODES * 4);
    int*    row_ptr = (int*)alloc((size_t)(N_NODES + 1) * 4);
    int*    csr     = (int*)alloc((size_t)NEDGE * 4);
    bf16_t* bgc     = (bf16_t*)alloc((size_t)LAYERS * DIM * 2);
    bf16_t* b1c     = (bf16_t*)alloc((size_t)LAYERS * DIM * 2);
    bf16_t* b2c     = (bf16_t*)alloc((size_t)LAYERS * DIM * 2);
    bf16_t* n1c     = (bf16_t*)alloc((size_t)LAYERS * DIM * 2);
    bf16_t* n2c     = (bf16_t*)alloc((size_t)LAYERS * DIM * 2);

    // prep_v also zeroes deg (runs before mega_setup's histogram)
    prep_v<<<(LAYERS * DIM * NH * 2 * 64 + 255) / 256, 256, 0, stream>>>(
        x_in, W_gat, att_s, att_d, vS, vD, deg);

    const int NTOT = N_NODES * DIM + LAYERS * DIM * HD + 2 * LAYERS * DIM * DIM
                   + 5 * LAYERS * DIM;
    const int convBlocks = (NTOT + 255) / 256;
    const int histBlocks = (NEDGE + 255) / 256;
    const int asdBlocks  = (N_NODES + 3) / 4;
    mega_setup<<<convBlocks + histBlocks + asdBlocks, 256, 0, stream>>>(
        x_in, W_gat, W1, W2, bias_g, b1, b2, n1w, n2w,
        xb, WmixP, W1P, W2P, bgc, b1c, b2c, n1c, n2c,
        ei, deg, vS, vD, a_sA, a_dA, x8a, convBlocks, histBlocks);

    scan_kernel<<<1, 1024, 0, stream>>>(deg, row_ptr, cursor);
    fill_kernel<<<(NEDGE + 255) / 256, 256, 0, stream>>>(ei, cursor, csr);

    unsigned short* x8cur[2] = {x8a, x8b};
    float* asCur[2] = {a_sA, a_sB};
    float* adCur[2] = {a_dA, a_dB};
    for (int l = 0; l < LAYERS; ++l) {
        int ci = l & 1, ni = (l + 1) & 1;
        gat_gather<<<(N_NODES * 64 + 255) / 256, 256, 0, stream>>>(
            row_ptr, csr, asCur[ci], adCur[ci], x8cur[ci], y);
        if (l < LAYERS - 1) {
            mix_ffn<0><<<NTILES, 256, 0, stream>>>(
                y, WmixP + (size_t)l * HD * DIM, bgc + (size_t)l * DIM,
                n1c + (size_t)l * DIM, xb,
                W1P + (size_t)l * DIM * DIM, b1c + (size_t)l * DIM,
                W2P + (size_t)l * DIM * DIM, b2c + (size_t)l * DIM,
                n2c + (size_t)l * DIM, xb,
                vS + (size_t)(l + 1) * HD, vD + (size_t)(l + 1) * HD,
                asCur[ni], adCur[ni], (unsigned char*)x8cur[ni]);
        } else {
            mix_ffn<1><<<NTILES, 256, 0, stream>>>(
                y, WmixP + (size_t)l * HD * DIM, bgc + (size_t)l * DIM,
                n1c + (size_t)l * DIM, xb,
                W1P + (size_t)l * DIM * DIM, b1c + (size_t)l * DIM,
                W2P + (size_t)l * DIM * DIM, b2c + (size_t)l * DIM,
                n2c + (size_t)l * DIM, d_out,
                nullptr, nullptr, nullptr, nullptr, nullptr);
        }
    }
}